// Round 3
// baseline (280.871 us; speedup 1.0000x reference)
//
#include <hip/hip_runtime.h>
#include <hip/hip_bf16.h>

#define BN 8192      // batch rows
#define MM 8199      // real rows (BN + 7 centers)
#define MP 8208      // padded to multiple of 16
#define HH 128       // feature dim
#define EE 256       // center embedding dim
#define JCHUNKS 64   // j-chunks (grid.y * 4 waves)
#define GX 128
#define GY 16
#define NBLK (GX * GY)
#define NUM_HIST 7

typedef __attribute__((ext_vector_type(8))) short short8;   // 8 bf16 = 4 VGPRs
typedef __attribute__((ext_vector_type(4))) float floatx4;

// ---- prep kernel: fuses {memset(tot/pos), centers GEMV, row-normalize, labp}
// blocks 0..2047: 4 batch rows each (wave per row) + zero 8 floats of tot/pos.
// block 2048: curr_centers into LDS, then normalize the 16 padded rows; zero bcount.
__global__ __launch_bounds__(256)
void prep_kernel(const float* __restrict__ reps,
                 const int* __restrict__ labels,
                 const float* __restrict__ centers,
                 const float* __restrict__ fc_w,
                 const float* __restrict__ fc_b,
                 __hip_bfloat16* __restrict__ rn,
                 int* __restrict__ labp,
                 float* __restrict__ tot,   // pos = tot + BN (contiguous)
                 int* __restrict__ bcount) {
  const int wid = threadIdx.x >> 6, lane = threadIdx.x & 63;
  const int b = blockIdx.x;
  if (b < 2048) {
    if (threadIdx.x < 8) tot[b * 8 + threadIdx.x] = 0.f;   // zeroes tot+pos (16384 floats)
    const int r = b * 4 + wid;
    float2 v = ((const float2*)(reps + (size_t)r * HH))[lane];
    float ss = v.x * v.x + v.y * v.y;
#pragma unroll
    for (int m = 1; m < 64; m <<= 1) ss += __shfl_xor(ss, m);
    float inv = 1.0f / fmaxf(sqrtf(ss), 1e-8f);
    __hip_bfloat162 h2;
    h2.x = __float2bfloat16(v.x * inv);
    h2.y = __float2bfloat16(v.y * inv);
    ((__hip_bfloat162*)(rn + (size_t)r * HH))[lane] = h2;
    if (lane == 0) labp[r] = labels[r];
  } else {
    // ---- block 2048: centers @ fc_w^T + fc_b  -> LDS, then padded rows
    __shared__ float currs[7 * HH];
    if (threadIdx.x == 0) *bcount = 0;
    for (int o = threadIdx.x; o < 7 * HH; o += 256) {
      int c = o >> 7, h = o & 127;
      const float4* ce = (const float4*)(centers + c * EE);
      const float4* w  = (const float4*)(fc_w + h * EE);
      float s = 0.f;
#pragma unroll 4
      for (int j = 0; j < EE / 4; ++j) {
        float4 a = ce[j], bb = w[j];
        s += a.x * bb.x + a.y * bb.y + a.z * bb.z + a.w * bb.w;
      }
      currs[o] = s + fc_b[h];
    }
    __syncthreads();
    // rows 8192..8207: wave wid handles 4 rows
    for (int k = 0; k < 4; ++k) {
      int c = wid * 4 + k;            // 0..15
      int r = BN + c;
      float2 v = make_float2(0.f, 0.f);
      if (c < 7) v = ((const float2*)(currs + c * HH))[lane];
      float ss = v.x * v.x + v.y * v.y;
#pragma unroll
      for (int m = 1; m < 64; m <<= 1) ss += __shfl_xor(ss, m);
      float inv = 1.0f / fmaxf(sqrtf(ss), 1e-8f);
      __hip_bfloat162 h2;
      h2.x = __float2bfloat16(v.x * inv);
      h2.y = __float2bfloat16(v.y * inv);
      ((__hip_bfloat162*)(rn + (size_t)r * HH))[lane] = h2;
      if (lane == 0) labp[r] = (r < MM) ? r - BN : -1;
    }
  }
}

// ---- main kernel: per i-row, tot_i = sum_j e_ij (j!=i), pos_i = same over label match
// e_ij = exp2((cos_ij - 1) * (0.5/TEMP) * log2e)   [global-max shift cancels in ratio]
// Padded j-columns (rn==0) contribute exactly exp2(-K2) each to tot; the loss
// phase subtracts the exact constant 9*exp2(-K2). Padded labp=-1 never matches.
// 4 waves/block, each wave owns j-chunk = blockIdx.y*4 + wid (64 chunks total).
// Register-double-buffered B prefetch hides L2 latency under MFMA+epilogue.
// Last-finishing block computes the scalar loss (saves a dispatch + gap).
// NOTE: launch_bounds min-waves MUST stay <=2 — (256,5) forced VGPR=48 and
// spilled afrag to scratch (FETCH 410MB, 3x slowdown). Kernel needs ~160 VGPR.
__global__ __launch_bounds__(256, 2)
void main_kernel(const __hip_bfloat16* __restrict__ rn,
                 const int* __restrict__ labp,
                 const int* __restrict__ labels,
                 float* __restrict__ tot,
                 float* __restrict__ pos,
                 int* __restrict__ bcount,
                 float* __restrict__ out) {
  __shared__ float red[128];   // [0..63]=tot for i-rows, [64..127]=pos
  __shared__ int amlast;
  const int lane = threadIdx.x & 63;
  const int wid  = threadIdx.x >> 6;
  const int q = lane >> 4, col = lane & 15;
  const int ibase = blockIdx.x * 64;
  const int chunk = (blockIdx.y << 2) | wid;   // 0..63
  const short* rns = (const short*)rn;

  if (threadIdx.x < 128) red[threadIdx.x] = 0.f;

  // A fragments: lane holds A[m=col][k = kk*32 + q*8 + 0..7]
  short8 afrag[4][4];
#pragma unroll
  for (int it = 0; it < 4; ++it) {
    const short8* p = (const short8*)(rns + (size_t)(ibase + it * 16 + col) * HH + q * 8);
    afrag[it][0] = p[0];
    afrag[it][1] = p[4];
    afrag[it][2] = p[8];
    afrag[it][3] = p[12];
  }
  // i-labels for C/D layout rows: row = q*4 + r
  int labi[4][4];
#pragma unroll
  for (int it = 0; it < 4; ++it)
#pragma unroll
    for (int r = 0; r < 4; ++r)
      labi[it][r] = labp[ibase + it * 16 + q * 4 + r];

  float stot[4][4] = {};
  float spos[4][4] = {};
  const float K2 = 10.30496147f;  // 0.5/0.07 * log2(e)

  // current B tile (register double-buffer partner loaded in-loop)
  const short* bptr = rns + (size_t)(chunk * 16 + col) * HH + q * 8;
  short8 bc0 = ((const short8*)bptr)[0];
  short8 bc1 = ((const short8*)bptr)[4];
  short8 bc2 = ((const short8*)bptr)[8];
  short8 bc3 = ((const short8*)bptr)[12];
  int labj = labp[chunk * 16 + col];
  int jb = chunk * 16;

  while (true) {
    const int jn = jb + 16 * JCHUNKS;
    const bool more = (jn < MP);
    // prefetch next tile (clamped to a safe in-bounds address when done)
    const short* np = more ? (bptr + 16 * JCHUNKS * HH) : (rns + col * HH + q * 8);
    short8 n0 = ((const short8*)np)[0];
    short8 n1 = ((const short8*)np)[4];
    short8 n2 = ((const short8*)np)[8];
    short8 n3 = ((const short8*)np)[12];
    const int labn = labp[more ? jn + col : col];

#pragma unroll
    for (int it = 0; it < 4; ++it) {
      floatx4 acc = {0.f, 0.f, 0.f, 0.f};
      acc = __builtin_amdgcn_mfma_f32_16x16x32_bf16(afrag[it][0], bc0, acc, 0, 0, 0);
      acc = __builtin_amdgcn_mfma_f32_16x16x32_bf16(afrag[it][1], bc1, acc, 0, 0, 0);
      acc = __builtin_amdgcn_mfma_f32_16x16x32_bf16(afrag[it][2], bc2, acc, 0, 0, 0);
      acc = __builtin_amdgcn_mfma_f32_16x16x32_bf16(afrag[it][3], bc3, acc, 0, 0, 0);
      const bool isdiag = (jb == ibase + it * 16);  // wave-uniform
#pragma unroll
      for (int r = 0; r < 4; ++r) {
        // C/D layout: row = q*4 + r, col = lane&15 → i = ibase+it*16+q*4+r, j = jb+col
        float e = __builtin_amdgcn_exp2f(fmaf(acc[r], K2, -K2));
        if (isdiag && (col == q * 4 + r)) e = 0.f;   // exclude diagonal j==i
        stot[it][r] += e;
        spos[it][r] += (labj == labi[it][r]) ? e : 0.f;
      }
    }
    if (!more) break;
    jb = jn;
    bptr = np;
    bc0 = n0; bc1 = n1; bc2 = n2; bc3 = n3;
    labj = labn;
  }

  __syncthreads();   // red[] init visible

  // reduce across the 16 column-lanes, then across waves via LDS,
  // then ONE global atomic per i-row per block.
#pragma unroll
  for (int it = 0; it < 4; ++it)
#pragma unroll
    for (int r = 0; r < 4; ++r) {
      float tt = stot[it][r], pp = spos[it][r];
#pragma unroll
      for (int m = 1; m <= 8; m <<= 1) {
        tt += __shfl_xor(tt, m);
        pp += __shfl_xor(pp, m);
      }
      if (col == 0) {
        int li = it * 16 + q * 4 + r;   // 0..63 local i-row
        atomicAdd(&red[li], tt);
        atomicAdd(&red[64 + li], pp);
      }
    }
  __syncthreads();
  if (threadIdx.x < 64)       atomicAdd(&tot[ibase + threadIdx.x], red[threadIdx.x]);
  else if (threadIdx.x < 128) atomicAdd(&pos[ibase + threadIdx.x - 64], red[threadIdx.x]);

  // ---- last-block loss phase
  __threadfence();
  __syncthreads();
  if (threadIdx.x == 0) {
    int old = atomicAdd(bcount, 1);
    amlast = (old == NBLK - 1) ? 1 : 0;
  }
  __syncthreads();
  if (!amlast) return;
  __threadfence();

  __shared__ int hist[NUM_HIST];
  __shared__ float s1[4], s2[4];
  const int tid = threadIdx.x;
  if (tid < NUM_HIST) hist[tid] = 0;
  __syncthreads();
  // ballot-based histogram: 7 ballots per 256-element stripe
  int c0 = 0, c1 = 0, c2 = 0, c3 = 0, c4 = 0, c5 = 0, c6 = 0;
  for (int i = tid; i < BN; i += 256) {
    int lab = labels[i];
    unsigned long long m0 = __ballot(lab == 0);
    unsigned long long m1 = __ballot(lab == 1);
    unsigned long long m2 = __ballot(lab == 2);
    unsigned long long m3 = __ballot(lab == 3);
    unsigned long long m4 = __ballot(lab == 4);
    unsigned long long m5 = __ballot(lab == 5);
    unsigned long long m6 = __ballot(lab == 6);
    if (lane == 0) {
      c0 += __popcll(m0); c1 += __popcll(m1); c2 += __popcll(m2);
      c3 += __popcll(m3); c4 += __popcll(m4); c5 += __popcll(m5);
      c6 += __popcll(m6);
    }
  }
  if (lane == 0) {
    atomicAdd(&hist[0], c0); atomicAdd(&hist[1], c1); atomicAdd(&hist[2], c2);
    atomicAdd(&hist[3], c3); atomicAdd(&hist[4], c4); atomicAdd(&hist[5], c5);
    atomicAdd(&hist[6], c6);
  }
  __syncthreads();
  const float epad9 = 9.0f * __builtin_amdgcn_exp2f(-K2);  // padded-column excess in tot
  float lsum = 0.f, msum = 0.f;
  for (int i = tid; i < BN; i += 256) {
    float t = __hip_atomic_load(&tot[i], __ATOMIC_RELAXED, __HIP_MEMORY_SCOPE_AGENT) - epad9;
    float p = __hip_atomic_load(&pos[i], __ATOMIC_RELAXED, __HIP_MEMORY_SCOPE_AGENT);
    float c = (float)hist[labels[i]];   // = sum(pos_mask*mask) exactly
    float pr = (p / t) / (c + 1e-8f);
    float lv = -logf(pr + 1e-8f);
    if (lv > 0.3f) { lsum += lv; msum += 1.f; }
  }
#pragma unroll
  for (int m = 1; m < 64; m <<= 1) {
    lsum += __shfl_xor(lsum, m);
    msum += __shfl_xor(msum, m);
  }
  if (lane == 0) { s1[wid] = lsum; s2[wid] = msum; }
  __syncthreads();
  if (tid == 0) {
    float a = s1[0] + s1[1] + s1[2] + s1[3];
    float b = s2[0] + s2[1] + s2[2] + s2[3];
    out[0] = a / (b + 1e-8f);
  }
}

extern "C" void kernel_launch(void* const* d_in, const int* in_sizes, int n_in,
                              void* d_out, int out_size, void* d_ws, size_t ws_size,
                              hipStream_t stream) {
  const float* reps    = (const float*)d_in[0];  // [8192,128]
  const int*   labels  = (const int*)d_in[1];    // [8192]
  const float* centers = (const float*)d_in[2];  // [7,256]
  const float* fc_w    = (const float*)d_in[3];  // [128,256]
  const float* fc_b    = (const float*)d_in[4];  // [128]
  float* out = (float*)d_out;

  char* ws = (char*)d_ws;
  int* bcount = (int*)(ws + 3584);
  int* labp   = (int*)(ws + 4096);                       // 8208*4
  __hip_bfloat16* rn = (__hip_bfloat16*)(ws + 40960);    // 8208*128*2 = 2101248 B
  float* tot = (float*)(ws + 40960 + 2101248);           // 8192*4
  float* pos = tot + BN;                                 // 8192*4 (contiguous after tot)

  prep_kernel<<<2049, 256, 0, stream>>>(reps, labels, centers, fc_w, fc_b,
                                        rn, labp, tot, bcount);
  main_kernel<<<dim3(GX, GY), 256, 0, stream>>>(rn, labp, labels, tot, pos, bcount, out);
}

// Round 4
// 185.668 us; speedup vs baseline: 1.5128x; 1.5128x over previous
//
#include <hip/hip_runtime.h>
#include <hip/hip_bf16.h>

#define BN 8192      // batch rows
#define MM 8199      // real rows (BN + 7 centers)
#define MP 8208      // padded to multiple of 16
#define HH 128       // feature dim
#define EE 256       // center embedding dim
#define JCHUNKS 64   // j-chunks (grid.y * 4 waves)
#define GX 256       // i-blocks (32 rows each)
#define GY 16
#define NUM_HIST 7

typedef __attribute__((ext_vector_type(8))) short short8;   // 8 bf16 = 4 VGPRs
typedef __attribute__((ext_vector_type(4))) float floatx4;

// ---- prep kernel: fuses {zero tot/pos, centers GEMV, row-normalize, labp}
// blocks 0..2047: 4 batch rows each (wave per row) + zero 8 floats of tot/pos.
// block 2048: curr_centers into LDS, then normalize the 16 padded rows.
__global__ __launch_bounds__(256)
void prep_kernel(const float* __restrict__ reps,
                 const int* __restrict__ labels,
                 const float* __restrict__ centers,
                 const float* __restrict__ fc_w,
                 const float* __restrict__ fc_b,
                 __hip_bfloat16* __restrict__ rn,
                 int* __restrict__ labp,
                 float* __restrict__ tot) {  // pos = tot + BN (contiguous)
  const int wid = threadIdx.x >> 6, lane = threadIdx.x & 63;
  const int b = blockIdx.x;
  if (b < 2048) {
    if (threadIdx.x < 8) tot[b * 8 + threadIdx.x] = 0.f;   // zeroes tot+pos (16384 floats)
    const int r = b * 4 + wid;
    float2 v = ((const float2*)(reps + (size_t)r * HH))[lane];
    float ss = v.x * v.x + v.y * v.y;
#pragma unroll
    for (int m = 1; m < 64; m <<= 1) ss += __shfl_xor(ss, m);
    float inv = 1.0f / fmaxf(sqrtf(ss), 1e-8f);
    __hip_bfloat162 h2;
    h2.x = __float2bfloat16(v.x * inv);
    h2.y = __float2bfloat16(v.y * inv);
    ((__hip_bfloat162*)(rn + (size_t)r * HH))[lane] = h2;
    if (lane == 0) labp[r] = labels[r];
  } else {
    // ---- block 2048: centers @ fc_w^T + fc_b  -> LDS, then padded rows
    __shared__ float currs[7 * HH];
    for (int o = threadIdx.x; o < 7 * HH; o += 256) {
      int c = o >> 7, h = o & 127;
      const float4* ce = (const float4*)(centers + c * EE);
      const float4* w  = (const float4*)(fc_w + h * EE);
      float s = 0.f;
#pragma unroll 4
      for (int j = 0; j < EE / 4; ++j) {
        float4 a = ce[j], bb = w[j];
        s += a.x * bb.x + a.y * bb.y + a.z * bb.z + a.w * bb.w;
      }
      currs[o] = s + fc_b[h];
    }
    __syncthreads();
    // rows 8192..8207: wave wid handles 4 rows
    for (int k = 0; k < 4; ++k) {
      int c = wid * 4 + k;            // 0..15
      int r = BN + c;
      float2 v = make_float2(0.f, 0.f);
      if (c < 7) v = ((const float2*)(currs + c * HH))[lane];
      float ss = v.x * v.x + v.y * v.y;
#pragma unroll
      for (int m = 1; m < 64; m <<= 1) ss += __shfl_xor(ss, m);
      float inv = 1.0f / fmaxf(sqrtf(ss), 1e-8f);
      __hip_bfloat162 h2;
      h2.x = __float2bfloat16(v.x * inv);
      h2.y = __float2bfloat16(v.y * inv);
      ((__hip_bfloat162*)(rn + (size_t)r * HH))[lane] = h2;
      if (lane == 0) labp[r] = (r < MM) ? r - BN : -1;
    }
  }
}

// ---- main kernel: per i-row, tot_i = sum_j e_ij (j!=i), pos_i = same over label match
// e_ij = exp2((cos_ij - 1) * (0.5/TEMP) * log2e)   [global-max shift cancels in ratio]
// Padded j-columns (rn==0) contribute exactly exp2(-K2) each to tot; the loss
// kernel subtracts the exact constant 9*exp2(-K2). Padded labp=-1 never matches.
// 32 i-rows per block (afrag[2][4] = 32 VGPR -> ~2x waves/SIMD vs 64-row version).
// 4 waves/block, each wave owns j-chunk = blockIdx.y*4 + wid (64 chunks total).
// Loop structure = round-2 measured form (loads at top, no manual prefetch).
// NOTE: NO __threadfence() anywhere — agent fences on gfx950 emit buffer_wbl2+
// buffer_inv (whole-L2 ops); 2048 of them tripled this kernel's duration (r3).
// NOTE: launch_bounds min-waves MUST stay <=2 — (256,5) forced VGPR=48 and
// spilled afrag to scratch (FETCH 410MB, 3x slowdown).
__global__ __launch_bounds__(256, 2)
void main_kernel(const __hip_bfloat16* __restrict__ rn,
                 const int* __restrict__ labp,
                 float* __restrict__ tot,
                 float* __restrict__ pos) {
  __shared__ float red[64];   // [0..31]=tot for i-rows, [32..63]=pos
  const int lane = threadIdx.x & 63;
  const int wid  = threadIdx.x >> 6;
  const int q = lane >> 4, col = lane & 15;
  const int ibase = blockIdx.x * 32;
  const int chunk = (blockIdx.y << 2) | wid;   // 0..63
  const short* rns = (const short*)rn;

  if (threadIdx.x < 64) red[threadIdx.x] = 0.f;

  // A fragments: lane holds A[m=col][k = kk*32 + q*8 + 0..7]
  short8 afrag[2][4];
#pragma unroll
  for (int it = 0; it < 2; ++it) {
    const short8* p = (const short8*)(rns + (size_t)(ibase + it * 16 + col) * HH + q * 8);
    afrag[it][0] = p[0];
    afrag[it][1] = p[4];
    afrag[it][2] = p[8];
    afrag[it][3] = p[12];
  }
  // i-labels for C/D layout rows: row = q*4 + r
  int labi[2][4];
#pragma unroll
  for (int it = 0; it < 2; ++it)
#pragma unroll
    for (int r = 0; r < 4; ++r)
      labi[it][r] = labp[ibase + it * 16 + q * 4 + r];

  float stot[2][4] = {};
  float spos[2][4] = {};
  const float K2 = 10.30496147f;  // 0.5/0.07 * log2(e)

  // pointer-increment B addressing: chunk strides 64 tiles = 1024 rows
  const short* bptr = rns + (size_t)(chunk * 16 + col) * HH + q * 8;
  const int* lptr = labp + chunk * 16 + col;

  for (int jb = chunk * 16; jb < MP; jb += 16 * JCHUNKS) {
    // B fragments: lane holds B[k = kk*32 + q*8 + 0..7][n=col] = rn[jb+col][k]
    short8 b0 = ((const short8*)bptr)[0];
    short8 b1 = ((const short8*)bptr)[4];
    short8 b2 = ((const short8*)bptr)[8];
    short8 b3 = ((const short8*)bptr)[12];
    const int labj = *lptr;
    bptr += 16 * JCHUNKS * HH;
    lptr += 16 * JCHUNKS;
#pragma unroll
    for (int it = 0; it < 2; ++it) {
      floatx4 acc = {0.f, 0.f, 0.f, 0.f};
      acc = __builtin_amdgcn_mfma_f32_16x16x32_bf16(afrag[it][0], b0, acc, 0, 0, 0);
      acc = __builtin_amdgcn_mfma_f32_16x16x32_bf16(afrag[it][1], b1, acc, 0, 0, 0);
      acc = __builtin_amdgcn_mfma_f32_16x16x32_bf16(afrag[it][2], b2, acc, 0, 0, 0);
      acc = __builtin_amdgcn_mfma_f32_16x16x32_bf16(afrag[it][3], b3, acc, 0, 0, 0);
      const bool isdiag = (jb == ibase + it * 16);  // wave-uniform
#pragma unroll
      for (int r = 0; r < 4; ++r) {
        // C/D layout: row = q*4 + r, col = lane&15 → i = ibase+it*16+q*4+r, j = jb+col
        float e = exp2f(fmaf(acc[r], K2, -K2));
        if (isdiag && (col == q * 4 + r)) e = 0.f;   // exclude diagonal j==i
        stot[it][r] += e;
        spos[it][r] += (labj == labi[it][r]) ? e : 0.f;
      }
    }
  }

  __syncthreads();   // red[] init visible

  // reduce across the 16 column-lanes, then across waves via LDS,
  // then ONE global atomic per i-row per block.
#pragma unroll
  for (int it = 0; it < 2; ++it)
#pragma unroll
    for (int r = 0; r < 4; ++r) {
      float tt = stot[it][r], pp = spos[it][r];
#pragma unroll
      for (int m = 1; m <= 8; m <<= 1) {
        tt += __shfl_xor(tt, m);
        pp += __shfl_xor(pp, m);
      }
      if (col == 0) {
        int li = it * 16 + q * 4 + r;   // 0..31 local i-row
        atomicAdd(&red[li], tt);
        atomicAdd(&red[32 + li], pp);
      }
    }
  __syncthreads();
  if (threadIdx.x < 32)      atomicAdd(&tot[ibase + threadIdx.x], red[threadIdx.x]);
  else if (threadIdx.x < 64) atomicAdd(&pos[ibase + threadIdx.x - 32], red[threadIdx.x]);
}

// ---- loss kernel: loss = sum(lv * (lv>0.3)) / (sum(lv>0.3) + eps),
//      lv = -log( ((pos/(tot-9*epad))/(hist[lab]+eps)) + eps )
__global__ __launch_bounds__(1024)
void loss_kernel(const float* __restrict__ tot,
                 const float* __restrict__ pos,
                 const int* __restrict__ labels,
                 float* __restrict__ out) {
  __shared__ int hist[NUM_HIST];
  __shared__ float s1[16], s2[16];
  const int tid = threadIdx.x;
  const int lane = tid & 63, wid = tid >> 6;
  if (tid < NUM_HIST) hist[tid] = 0;
  __syncthreads();
  // ballot-based histogram: 7 ballots per 1024-element stripe, no LDS contention
  int c0 = 0, c1 = 0, c2 = 0, c3 = 0, c4 = 0, c5 = 0, c6 = 0;
  for (int i = tid; i < BN; i += 1024) {
    int lab = labels[i];
    unsigned long long m0 = __ballot(lab == 0);
    unsigned long long m1 = __ballot(lab == 1);
    unsigned long long m2 = __ballot(lab == 2);
    unsigned long long m3 = __ballot(lab == 3);
    unsigned long long m4 = __ballot(lab == 4);
    unsigned long long m5 = __ballot(lab == 5);
    unsigned long long m6 = __ballot(lab == 6);
    if (lane == 0) {
      c0 += __popcll(m0); c1 += __popcll(m1); c2 += __popcll(m2);
      c3 += __popcll(m3); c4 += __popcll(m4); c5 += __popcll(m5);
      c6 += __popcll(m6);
    }
  }
  if (lane == 0) {
    atomicAdd(&hist[0], c0); atomicAdd(&hist[1], c1); atomicAdd(&hist[2], c2);
    atomicAdd(&hist[3], c3); atomicAdd(&hist[4], c4); atomicAdd(&hist[5], c5);
    atomicAdd(&hist[6], c6);
  }
  __syncthreads();
  const float K2 = 10.30496147f;
  const float epad9 = 9.0f * exp2f(-K2);   // padded-column excess in tot
  float lsum = 0.f, msum = 0.f;
  for (int i = tid; i < BN; i += 1024) {
    float t = tot[i] - epad9;
    float p = pos[i];
    float c = (float)hist[labels[i]];   // = sum(pos_mask*mask) exactly
    float pr = (p / t) / (c + 1e-8f);
    float lv = -logf(pr + 1e-8f);
    if (lv > 0.3f) { lsum += lv; msum += 1.f; }
  }
#pragma unroll
  for (int m = 1; m < 64; m <<= 1) {
    lsum += __shfl_xor(lsum, m);
    msum += __shfl_xor(msum, m);
  }
  if (lane == 0) { s1[wid] = lsum; s2[wid] = msum; }
  __syncthreads();
  if (wid == 0) {
    float a = (lane < 16) ? s1[lane] : 0.f;
    float b = (lane < 16) ? s2[lane] : 0.f;
#pragma unroll
    for (int m = 1; m < 16; m <<= 1) {
      a += __shfl_xor(a, m);
      b += __shfl_xor(b, m);
    }
    if (lane == 0) out[0] = a / (b + 1e-8f);
  }
}

extern "C" void kernel_launch(void* const* d_in, const int* in_sizes, int n_in,
                              void* d_out, int out_size, void* d_ws, size_t ws_size,
                              hipStream_t stream) {
  const float* reps    = (const float*)d_in[0];  // [8192,128]
  const int*   labels  = (const int*)d_in[1];    // [8192]
  const float* centers = (const float*)d_in[2];  // [7,256]
  const float* fc_w    = (const float*)d_in[3];  // [128,256]
  const float* fc_b    = (const float*)d_in[4];  // [128]
  float* out = (float*)d_out;

  char* ws = (char*)d_ws;
  int* labp   = (int*)(ws + 4096);                       // 8208*4
  __hip_bfloat16* rn = (__hip_bfloat16*)(ws + 40960);    // 8208*128*2 = 2101248 B
  float* tot = (float*)(ws + 40960 + 2101248);           // 8192*4
  float* pos = tot + BN;                                 // 8192*4 (contiguous after tot)

  prep_kernel<<<2049, 256, 0, stream>>>(reps, labels, centers, fc_w, fc_b, rn, labp, tot);
  main_kernel<<<dim3(GX, GY), 256, 0, stream>>>(rn, labp, tot, pos);
  loss_kernel<<<1, 1024, 0, stream>>>(tot, pos, labels, out);
}

// Round 5
// 162.288 us; speedup vs baseline: 1.7307x; 1.1441x over previous
//
#include <hip/hip_runtime.h>
#include <hip/hip_bf16.h>

#define BN 8192      // batch rows
#define MM 8199      // real rows (BN + 7 centers)
#define MP 8208      // padded to multiple of 16
#define HH 128       // feature dim
#define EE 256       // center embedding dim
#define JCHUNKS 64   // j-chunks (grid.y * 4 waves)
#define GX 128       // i-blocks (64 rows each)
#define GY 16
#define NUM_HIST 7

typedef __attribute__((ext_vector_type(8))) short short8;   // 8 bf16 = 4 VGPRs
typedef __attribute__((ext_vector_type(4))) float floatx4;

// ---- prep kernel: fuses {zero tot/pos, centers GEMV, row-normalize, labp}
// blocks 0..2047: 4 batch rows each (wave per row) + zero 8 floats of tot/pos.
// block 2048: curr_centers into LDS, then normalize the 16 padded rows.
__global__ __launch_bounds__(256)
void prep_kernel(const float* __restrict__ reps,
                 const int* __restrict__ labels,
                 const float* __restrict__ centers,
                 const float* __restrict__ fc_w,
                 const float* __restrict__ fc_b,
                 __hip_bfloat16* __restrict__ rn,
                 int* __restrict__ labp,
                 float* __restrict__ tot) {  // pos = tot + BN (contiguous)
  const int wid = threadIdx.x >> 6, lane = threadIdx.x & 63;
  const int b = blockIdx.x;
  if (b < 2048) {
    if (threadIdx.x < 8) tot[b * 8 + threadIdx.x] = 0.f;   // zeroes tot+pos (16384 floats)
    const int r = b * 4 + wid;
    float2 v = ((const float2*)(reps + (size_t)r * HH))[lane];
    float ss = v.x * v.x + v.y * v.y;
#pragma unroll
    for (int m = 1; m < 64; m <<= 1) ss += __shfl_xor(ss, m);
    float inv = 1.0f / fmaxf(sqrtf(ss), 1e-8f);
    __hip_bfloat162 h2;
    h2.x = __float2bfloat16(v.x * inv);
    h2.y = __float2bfloat16(v.y * inv);
    ((__hip_bfloat162*)(rn + (size_t)r * HH))[lane] = h2;
    if (lane == 0) labp[r] = labels[r];
  } else {
    // ---- block 2048: centers @ fc_w^T + fc_b  -> LDS, then padded rows
    __shared__ float currs[7 * HH];
    for (int o = threadIdx.x; o < 7 * HH; o += 256) {
      int c = o >> 7, h = o & 127;
      const float4* ce = (const float4*)(centers + c * EE);
      const float4* w  = (const float4*)(fc_w + h * EE);
      float s = 0.f;
#pragma unroll 4
      for (int j = 0; j < EE / 4; ++j) {
        float4 a = ce[j], bb = w[j];
        s += a.x * bb.x + a.y * bb.y + a.z * bb.z + a.w * bb.w;
      }
      currs[o] = s + fc_b[h];
    }
    __syncthreads();
    // rows 8192..8207: wave wid handles 4 rows
    for (int k = 0; k < 4; ++k) {
      int c = wid * 4 + k;            // 0..15
      int r = BN + c;
      float2 v = make_float2(0.f, 0.f);
      if (c < 7) v = ((const float2*)(currs + c * HH))[lane];
      float ss = v.x * v.x + v.y * v.y;
#pragma unroll
      for (int m = 1; m < 64; m <<= 1) ss += __shfl_xor(ss, m);
      float inv = 1.0f / fmaxf(sqrtf(ss), 1e-8f);
      __hip_bfloat162 h2;
      h2.x = __float2bfloat16(v.x * inv);
      h2.y = __float2bfloat16(v.y * inv);
      ((__hip_bfloat162*)(rn + (size_t)r * HH))[lane] = h2;
      if (lane == 0) labp[r] = (r < MM) ? r - BN : -1;
    }
  }
}

// ---- main kernel: per i-row, tot_i = sum_j e_ij (j!=i), pos_i = same over label match
// e_ij = exp2((cos_ij - 1) * (0.5/TEMP) * log2e)   [global-max shift cancels in ratio]
// Padded j-columns (rn==0) contribute exactly exp2(-K2) each to tot; the loss
// kernel subtracts the exact constant 9*exp2(-K2). Padded labp=-1 never matches.
// Structure = round-2 measured form (64 i-rows/block, it=4, loads at loop top).
// r4 A/B: halving tile + doubling occupancy made it SLOWER -> VALU-issue-bound,
// so the fix is fewer epilogue instructions, not more waves:
//   exp2f() -> __builtin_amdgcn_exp2f (single v_exp_f32; OCML exp2f is a
//   multi-instruction precise sequence and sat on the serial chain 67M times).
// NOTE: NO __threadfence() anywhere — agent fences on gfx950 emit buffer_wbl2+
// buffer_inv (whole-L2 ops); 2048 of them tripled this kernel's duration (r3).
// NOTE: launch_bounds min-waves MUST stay <=2 — (256,5) forced VGPR=48 and
// spilled afrag to scratch (FETCH 410MB, 3x slowdown).
__global__ __launch_bounds__(256, 2)
void main_kernel(const __hip_bfloat16* __restrict__ rn,
                 const int* __restrict__ labp,
                 float* __restrict__ tot,
                 float* __restrict__ pos) {
  __shared__ float red[128];   // [0..63]=tot for i-rows, [64..127]=pos
  const int lane = threadIdx.x & 63;
  const int wid  = threadIdx.x >> 6;
  const int q = lane >> 4, col = lane & 15;
  const int ibase = blockIdx.x * 64;
  const int chunk = (blockIdx.y << 2) | wid;   // 0..63
  const short* rns = (const short*)rn;

  if (threadIdx.x < 128) red[threadIdx.x] = 0.f;

  // A fragments: lane holds A[m=col][k = kk*32 + q*8 + 0..7]
  short8 afrag[4][4];
#pragma unroll
  for (int it = 0; it < 4; ++it) {
    const short8* p = (const short8*)(rns + (size_t)(ibase + it * 16 + col) * HH + q * 8);
    afrag[it][0] = p[0];
    afrag[it][1] = p[4];
    afrag[it][2] = p[8];
    afrag[it][3] = p[12];
  }
  // i-labels for C/D layout rows: row = q*4 + r
  int labi[4][4];
#pragma unroll
  for (int it = 0; it < 4; ++it)
#pragma unroll
    for (int r = 0; r < 4; ++r)
      labi[it][r] = labp[ibase + it * 16 + q * 4 + r];

  float stot[4][4] = {};
  float spos[4][4] = {};
  const float K2 = 10.30496147f;  // 0.5/0.07 * log2(e)

  // pointer-increment B addressing: chunk strides 64 tiles = 1024 rows
  const short* bptr = rns + (size_t)(chunk * 16 + col) * HH + q * 8;
  const int* lptr = labp + chunk * 16 + col;

  for (int jb = chunk * 16; jb < MP; jb += 16 * JCHUNKS) {
    // B fragments: lane holds B[k = kk*32 + q*8 + 0..7][n=col] = rn[jb+col][k]
    short8 b0 = ((const short8*)bptr)[0];
    short8 b1 = ((const short8*)bptr)[4];
    short8 b2 = ((const short8*)bptr)[8];
    short8 b3 = ((const short8*)bptr)[12];
    const int labj = *lptr;
    bptr += 16 * JCHUNKS * HH;
    lptr += 16 * JCHUNKS;
#pragma unroll
    for (int it = 0; it < 4; ++it) {
      floatx4 acc = {0.f, 0.f, 0.f, 0.f};
      acc = __builtin_amdgcn_mfma_f32_16x16x32_bf16(afrag[it][0], b0, acc, 0, 0, 0);
      acc = __builtin_amdgcn_mfma_f32_16x16x32_bf16(afrag[it][1], b1, acc, 0, 0, 0);
      acc = __builtin_amdgcn_mfma_f32_16x16x32_bf16(afrag[it][2], b2, acc, 0, 0, 0);
      acc = __builtin_amdgcn_mfma_f32_16x16x32_bf16(afrag[it][3], b3, acc, 0, 0, 0);
      const bool isdiag = (jb == ibase + it * 16);  // wave-uniform
#pragma unroll
      for (int r = 0; r < 4; ++r) {
        // C/D layout: row = q*4 + r, col = lane&15 → i = ibase+it*16+q*4+r, j = jb+col
        float e = __builtin_amdgcn_exp2f(fmaf(acc[r], K2, -K2));  // raw v_exp_f32
        if (isdiag && (col == q * 4 + r)) e = 0.f;   // exclude diagonal j==i
        float m = (labj == labi[it][r]) ? 1.0f : 0.0f;
        stot[it][r] += e;
        spos[it][r] = fmaf(m, e, spos[it][r]);
      }
    }
  }

  __syncthreads();   // red[] init visible

  // reduce across the 16 column-lanes, then across waves via LDS,
  // then ONE global atomic per i-row per block.
#pragma unroll
  for (int it = 0; it < 4; ++it)
#pragma unroll
    for (int r = 0; r < 4; ++r) {
      float tt = stot[it][r], pp = spos[it][r];
#pragma unroll
      for (int m = 1; m <= 8; m <<= 1) {
        tt += __shfl_xor(tt, m);
        pp += __shfl_xor(pp, m);
      }
      if (col == 0) {
        int li = it * 16 + q * 4 + r;   // 0..63 local i-row
        atomicAdd(&red[li], tt);
        atomicAdd(&red[64 + li], pp);
      }
    }
  __syncthreads();
  if (threadIdx.x < 64)       atomicAdd(&tot[ibase + threadIdx.x], red[threadIdx.x]);
  else if (threadIdx.x < 128) atomicAdd(&pos[ibase + threadIdx.x - 64], red[threadIdx.x]);
}

// ---- loss kernel: loss = sum(lv * (lv>0.3)) / (sum(lv>0.3) + eps),
//      lv = -log( ((pos/(tot-9*epad))/(hist[lab]+eps)) + eps )
__global__ __launch_bounds__(1024)
void loss_kernel(const float* __restrict__ tot,
                 const float* __restrict__ pos,
                 const int* __restrict__ labels,
                 float* __restrict__ out) {
  __shared__ int hist[NUM_HIST];
  __shared__ float s1[16], s2[16];
  const int tid = threadIdx.x;
  const int lane = tid & 63, wid = tid >> 6;
  if (tid < NUM_HIST) hist[tid] = 0;
  __syncthreads();
  // ballot-based histogram: 7 ballots per 1024-element stripe, no LDS contention
  int c0 = 0, c1 = 0, c2 = 0, c3 = 0, c4 = 0, c5 = 0, c6 = 0;
  for (int i = tid; i < BN; i += 1024) {
    int lab = labels[i];
    unsigned long long m0 = __ballot(lab == 0);
    unsigned long long m1 = __ballot(lab == 1);
    unsigned long long m2 = __ballot(lab == 2);
    unsigned long long m3 = __ballot(lab == 3);
    unsigned long long m4 = __ballot(lab == 4);
    unsigned long long m5 = __ballot(lab == 5);
    unsigned long long m6 = __ballot(lab == 6);
    if (lane == 0) {
      c0 += __popcll(m0); c1 += __popcll(m1); c2 += __popcll(m2);
      c3 += __popcll(m3); c4 += __popcll(m4); c5 += __popcll(m5);
      c6 += __popcll(m6);
    }
  }
  if (lane == 0) {
    atomicAdd(&hist[0], c0); atomicAdd(&hist[1], c1); atomicAdd(&hist[2], c2);
    atomicAdd(&hist[3], c3); atomicAdd(&hist[4], c4); atomicAdd(&hist[5], c5);
    atomicAdd(&hist[6], c6);
  }
  __syncthreads();
  const float K2 = 10.30496147f;
  const float epad9 = 9.0f * exp2f(-K2);   // padded-column excess in tot
  float lsum = 0.f, msum = 0.f;
  for (int i = tid; i < BN; i += 1024) {
    float t = tot[i] - epad9;
    float p = pos[i];
    float c = (float)hist[labels[i]];   // = sum(pos_mask*mask) exactly
    float pr = (p / t) / (c + 1e-8f);
    float lv = -logf(pr + 1e-8f);
    if (lv > 0.3f) { lsum += lv; msum += 1.f; }
  }
#pragma unroll
  for (int m = 1; m < 64; m <<= 1) {
    lsum += __shfl_xor(lsum, m);
    msum += __shfl_xor(msum, m);
  }
  if (lane == 0) { s1[wid] = lsum; s2[wid] = msum; }
  __syncthreads();
  if (wid == 0) {
    float a = (lane < 16) ? s1[lane] : 0.f;
    float b = (lane < 16) ? s2[lane] : 0.f;
#pragma unroll
    for (int m = 1; m < 16; m <<= 1) {
      a += __shfl_xor(a, m);
      b += __shfl_xor(b, m);
    }
    if (lane == 0) out[0] = a / (b + 1e-8f);
  }
}

extern "C" void kernel_launch(void* const* d_in, const int* in_sizes, int n_in,
                              void* d_out, int out_size, void* d_ws, size_t ws_size,
                              hipStream_t stream) {
  const float* reps    = (const float*)d_in[0];  // [8192,128]
  const int*   labels  = (const int*)d_in[1];    // [8192]
  const float* centers = (const float*)d_in[2];  // [7,256]
  const float* fc_w    = (const float*)d_in[3];  // [128,256]
  const float* fc_b    = (const float*)d_in[4];  // [128]
  float* out = (float*)d_out;

  char* ws = (char*)d_ws;
  int* labp   = (int*)(ws + 4096);                       // 8208*4
  __hip_bfloat16* rn = (__hip_bfloat16*)(ws + 40960);    // 8208*128*2 = 2101248 B
  float* tot = (float*)(ws + 40960 + 2101248);           // 8192*4
  float* pos = tot + BN;                                 // 8192*4 (contiguous after tot)

  prep_kernel<<<2049, 256, 0, stream>>>(reps, labels, centers, fc_w, fc_b, rn, labp, tot);
  main_kernel<<<dim3(GX, GY), 256, 0, stream>>>(rn, labp, tot, pos);
  loss_kernel<<<1, 1024, 0, stream>>>(tot, pos, labels, out);
}